// Round 3
// baseline (2967.048 us; speedup 1.0000x reference)
//
#include <hip/hip_runtime.h>
#include <math.h>

__device__ __forceinline__ float silu_f(float v) { return v / (1.0f + expf(-v)); }

// ---------------- GEMM (1x1 conv partial):
// out[(z*outC+m)*4096 + n] (op)= sum_k W[m*ldW+k] * in[(z*K+k)*4096 + n]
// ACC: 0 = init with bias[m], 1 = accumulate onto existing out
// FIN: 0 = none, 1 = SiLU, 2 = gate-multiply by y (gA: ch<512 half, gB: ch>=512 half)
template <int ACC, int FIN>
__global__ __launch_bounds__(256)
void gemm1x1(const float* __restrict__ in, const float* __restrict__ W, int ldW,
             const float* __restrict__ bias, float* __restrict__ out, int outC,
             const float* __restrict__ gA, const float* __restrict__ gB, int b0,
             int K)
{
    __shared__ float As[16][128];   // As[k][m]
    __shared__ float Bs[16][132];   // Bs[k][n] (+4 pad)
    const int t  = threadIdx.x;
    const int z  = blockIdx.z;
    const int m0 = blockIdx.y * 128;
    const int n0 = blockIdx.x * 128;
    const int tx = t & 15, ty = t >> 4;
    const int ar = t >> 1, ac = (t & 1) * 8;
    const int kb = t >> 4, cb = (t & 15) * 8;
    const float* Ap = W + (size_t)(m0 + ar) * ldW + ac;
    const float* Bp = in + ((size_t)z * K + kb) * 4096 + n0 + cb;

    float acc[8][8];
#pragma unroll
    for (int i = 0; i < 8; ++i)
#pragma unroll
        for (int j = 0; j < 8; ++j) acc[i][j] = 0.0f;

    for (int k0 = 0; k0 < K; k0 += 16) {
        float4 a0 = *(const float4*)(Ap + k0);
        float4 a1 = *(const float4*)(Ap + k0 + 4);
        float4 b0v = *(const float4*)(Bp + (size_t)k0 * 4096);
        float4 b1v = *(const float4*)(Bp + (size_t)k0 * 4096 + 4);
        As[ac + 0][ar] = a0.x; As[ac + 1][ar] = a0.y;
        As[ac + 2][ar] = a0.z; As[ac + 3][ar] = a0.w;
        As[ac + 4][ar] = a1.x; As[ac + 5][ar] = a1.y;
        As[ac + 6][ar] = a1.z; As[ac + 7][ar] = a1.w;
        *(float4*)&Bs[kb][cb]     = b0v;
        *(float4*)&Bs[kb][cb + 4] = b1v;
        __syncthreads();
#pragma unroll
        for (int kk = 0; kk < 16; ++kk) {
            float av[8], bv[8];
            *(float4*)&av[0] = *(const float4*)&As[kk][ty * 8];
            *(float4*)&av[4] = *(const float4*)&As[kk][ty * 8 + 4];
            *(float4*)&bv[0] = *(const float4*)&Bs[kk][tx * 8];
            *(float4*)&bv[4] = *(const float4*)&Bs[kk][tx * 8 + 4];
#pragma unroll
            for (int i = 0; i < 8; ++i)
#pragma unroll
                for (int j = 0; j < 8; ++j)
                    acc[i][j] = fmaf(av[i], bv[j], acc[i][j]);
        }
        __syncthreads();
    }

#pragma unroll
    for (int i = 0; i < 8; ++i) {
        const int m = m0 + ty * 8 + i;
        const size_t ob = ((size_t)z * outC + m) * 4096 + n0 + tx * 8;
        float v[8];
        if (ACC == 0) {
            const float bs = bias[m];
#pragma unroll
            for (int j = 0; j < 8; ++j) v[j] = acc[i][j] + bs;
        } else {
            float4 o0 = *(const float4*)&out[ob];
            float4 o1 = *(const float4*)&out[ob + 4];
            v[0] = acc[i][0] + o0.x; v[1] = acc[i][1] + o0.y;
            v[2] = acc[i][2] + o0.z; v[3] = acc[i][3] + o0.w;
            v[4] = acc[i][4] + o1.x; v[5] = acc[i][5] + o1.y;
            v[6] = acc[i][6] + o1.z; v[7] = acc[i][7] + o1.w;
        }
        if (FIN == 1) {
#pragma unroll
            for (int j = 0; j < 8; ++j) v[j] = silu_f(v[j]);
        } else if (FIN == 2) {
            const size_t gb = (size_t)(b0 + z);
            const float* mp = (m < 512)
                ? gA + (gb * 512 + m) * 4096 + n0 + tx * 8
                : gB + (gb * 512 + (m - 512)) * 4096 + n0 + tx * 8;
#pragma unroll
            for (int j = 0; j < 8; ++j) v[j] *= mp[j];
        }
        *(float4*)&out[ob]     = *(float4*)&v[0];
        *(float4*)&out[ob + 4] = *(float4*)&v[4];
    }
}

// ---------------- fused separable 5x5 TMaxAvg pool on compact [8,256,64,64]
__global__ __launch_bounds__(256)
void pool_tma_fused(const float* __restrict__ in, float* __restrict__ out)
{
    __shared__ float xs[4096];
    __shared__ float hm[4096];
    __shared__ float hs[4096];
    const size_t base = (size_t)blockIdx.x * 4096;
    const int t = threadIdx.x;
#pragma unroll
    for (int i = t; i < 1024; i += 256)
        ((float4*)xs)[i] = ((const float4*)(in + base))[i];
    __syncthreads();
#pragma unroll
    for (int i = t; i < 4096; i += 256) {
        int x = i & 63;
        float mx = -INFINITY, sm = 0.0f;
#pragma unroll
        for (int dx = -2; dx <= 2; ++dx) {
            int xx = x + dx;
            if (0 <= xx && xx < 64) { float v = xs[i + dx]; mx = fmaxf(mx, v); sm += v; }
        }
        hm[i] = mx; hs[i] = sm;
    }
    __syncthreads();
#pragma unroll
    for (int i = t; i < 4096; i += 256) {
        int y = i >> 6;
        float mx = -INFINITY, sm = 0.0f;
#pragma unroll
        for (int dy = -2; dy <= 2; ++dy) {
            int yy = y + dy;
            if (0 <= yy && yy < 64) { mx = fmaxf(mx, hm[i + dy * 64]); sm += hs[i + dy * 64]; }
        }
        out[base + i] = 0.9f * mx + 0.1f * (sm * (1.0f / 25.0f));
    }
}

// ---------------- fused separable 5x5 RW pool on compact [8,256,64,64]
__global__ __launch_bounds__(256)
void pool_rw_fused(const float* __restrict__ in, const float* __restrict__ cval,
                   float* __restrict__ out)
{
    __shared__ float xs[4096];
    __shared__ float hx[4096];
    __shared__ float he[4096];
    const size_t base = (size_t)blockIdx.x * 4096;
    const int t = threadIdx.x;
    const float cc = cval[0];
#pragma unroll
    for (int i = t; i < 1024; i += 256)
        ((float4*)xs)[i] = ((const float4*)(in + base))[i];
    __syncthreads();
#pragma unroll
    for (int i = t; i < 4096; i += 256) {
        int x = i & 63;
        float se = 0.0f, sx = 0.0f;
#pragma unroll
        for (int dx = -2; dx <= 2; ++dx) {
            int xx = x + dx;
            if (0 <= xx && xx < 64) {
                float v = xs[i + dx];
                float e = expf(v - cc);
                se += e; sx += e * v;
            }
        }
        hx[i] = sx; he[i] = se;
    }
    __syncthreads();
#pragma unroll
    for (int i = t; i < 4096; i += 256) {
        int y = i >> 6;
        float se = 0.0f, sx = 0.0f;
#pragma unroll
        for (int dy = -2; dy <= 2; ++dy) {
            int yy = y + dy;
            if (0 <= yy && yy < 64) { sx += hx[i + dy * 64]; se += he[i + dy * 64]; }
        }
        out[base + i] = sx / (se + 1e-6f);
    }
}

// ---------------- global max over compact 8,388,608-element tensor
__global__ void rmax1(const float* __restrict__ in, float* __restrict__ part)
{
    __shared__ float sm[256];
    int tid = threadIdx.x;
    float m = -INFINITY;
    for (size_t i = (size_t)blockIdx.x * 256 + tid; i < 8388608; i += 65536)
        m = fmaxf(m, in[i]);
    sm[tid] = m; __syncthreads();
    for (int s = 128; s > 0; s >>= 1) {
        if (tid < s) sm[tid] = fmaxf(sm[tid], sm[tid + s]);
        __syncthreads();
    }
    if (tid == 0) part[blockIdx.x] = sm[0];
}

__global__ void rmax2(const float* __restrict__ part, float* __restrict__ cval)
{
    __shared__ float sm[256];
    int tid = threadIdx.x;
    sm[tid] = part[tid]; __syncthreads();
    for (int s = 128; s > 0; s >>= 1) {
        if (tid < s) sm[tid] = fmaxf(sm[tid], sm[tid + s]);
        __syncthreads();
    }
    if (tid == 0) cval[0] = sm[0];
}

// ---------------- fused LSKA depthwise chain for a batch-PAIR (b0, b0+1).
// y is split: channels [0,512) in YF ([8,512,4096]), [512,1024) in YS.
// Output a4 compact [2,1024,4096]. blockIdx.x = z*1024 + ch, z in {0,1}.
__global__ __launch_bounds__(256)
void lska_dw_pair(const float* __restrict__ YF, const float* __restrict__ YS, int b0,
                  const float* __restrict__ wh1, const float* __restrict__ bh1,
                  const float* __restrict__ wv1, const float* __restrict__ bv1,
                  const float* __restrict__ wh2, const float* __restrict__ bh2,
                  const float* __restrict__ wv2, const float* __restrict__ bv2,
                  float* __restrict__ out)
{
    __shared__ float buf0[4096];
    __shared__ float buf1[4096];
    const int bi = blockIdx.x;
    const int z = bi >> 10, c = bi & 1023;
    const size_t gb = (size_t)(b0 + z);
    const float* src = (c < 512) ? YF + (gb * 512 + c) * 4096
                                 : YS + (gb * 512 + (c - 512)) * 4096;
    float* dst = out + (size_t)bi * 4096;
    const int t = threadIdx.x;
#pragma unroll
    for (int i = t; i < 1024; i += 256)
        ((float4*)buf0)[i] = ((const float4*)src)[i];
    __syncthreads();
    {   // phase 1: horizontal dil=1
        float w0 = wh1[c * 3], w1 = wh1[c * 3 + 1], w2 = wh1[c * 3 + 2], bb = bh1[c];
#pragma unroll
        for (int i = t; i < 4096; i += 256) {
            int x = i & 63;
            float a = fmaf(w1, buf0[i], bb);
            if (x >= 1)  a = fmaf(w0, buf0[i - 1], a);
            if (x <= 62) a = fmaf(w2, buf0[i + 1], a);
            buf1[i] = a;
        }
    }
    __syncthreads();
    {   // phase 2: vertical dil=1
        float w0 = wv1[c * 3], w1 = wv1[c * 3 + 1], w2 = wv1[c * 3 + 2], bb = bv1[c];
#pragma unroll
        for (int i = t; i < 4096; i += 256) {
            int y = i >> 6;
            float a = fmaf(w1, buf1[i], bb);
            if (y >= 1)  a = fmaf(w0, buf1[i - 64], a);
            if (y <= 62) a = fmaf(w2, buf1[i + 64], a);
            buf0[i] = a;
        }
    }
    __syncthreads();
    {   // phase 3: horizontal dil=2
        float w0 = wh2[c * 3], w1 = wh2[c * 3 + 1], w2 = wh2[c * 3 + 2], bb = bh2[c];
#pragma unroll
        for (int i = t; i < 4096; i += 256) {
            int x = i & 63;
            float a = fmaf(w1, buf0[i], bb);
            if (x >= 2)  a = fmaf(w0, buf0[i - 2], a);
            if (x <= 61) a = fmaf(w2, buf0[i + 2], a);
            buf1[i] = a;
        }
    }
    __syncthreads();
    {   // phase 4: vertical dil=2
        float w0 = wv2[c * 3], w1 = wv2[c * 3 + 1], w2 = wv2[c * 3 + 2], bb = bv2[c];
#pragma unroll
        for (int i = t; i < 4096; i += 256) {
            int y = i >> 6;
            float a = fmaf(w1, buf1[i], bb);
            if (y >= 2)  a = fmaf(w0, buf1[i - 128], a);
            if (y <= 61) a = fmaf(w2, buf1[i + 128], a);
            dst[i] = a;
        }
    }
}

extern "C" void kernel_launch(void* const* d_in, const int* in_sizes, int n_in,
                              void* d_out, int out_size, void* d_ws, size_t ws_size,
                              hipStream_t stream)
{
    const float* x       = (const float*)d_in[0];
    const float* w_sta   = (const float*)d_in[1];
    const float* b_sta   = (const float*)d_in[2];
    const float* w_cv1   = (const float*)d_in[3];
    const float* b_cv1   = (const float*)d_in[4];
    const float* w_cv2   = (const float*)d_in[5];
    const float* b_cv2   = (const float*)d_in[6];
    const float* w_cvend = (const float*)d_in[7];
    const float* b_cvend = (const float*)d_in[8];
    const float* w_dwh   = (const float*)d_in[9];
    const float* b_dwh   = (const float*)d_in[10];
    const float* w_dwv   = (const float*)d_in[11];
    const float* b_dwv   = (const float*)d_in[12];
    const float* w_ddwh  = (const float*)d_in[13];
    const float* b_ddwh  = (const float*)d_in[14];
    const float* w_ddwv  = (const float*)d_in[15];
    const float* b_ddwv  = (const float*)d_in[16];
    const float* w_c1    = (const float*)d_in[17];
    const float* b_c1    = (const float*)d_in[18];
    float* out = (float*)d_out;

    // ws layout (floats), TOTAL = 33,554,432 floats = exactly 128 MiB:
    //   A  [0        .. 8388608)   stage slot / a4-pair scratch
    //   B  [8388608  .. 16777216)  stage slot / g-pair scratch
    //   YS [16777216 .. 33554432)  y second half (cv2 output), [8,512,4096]
    // YF (y first half, cv1 output) lives in d_out [8,512,4096] and is
    // overwritten per batch-pair by cvend only after that pair consumed it.
    // PT/CV (max-reduce partials, 260 floats) live in d_out's tail, which is
    // dead during the rw branch (runs before anything writes YF).
    float* A  = (float*)d_ws;
    float* B  = A + 8388608;
    float* YS = A + 16777216;
    float* YF = out;
    float* PT = out + 16776704;   // 256 floats
    float* CV = out + 16776960;   // 3 floats (tail of d_out)

    dim3 blk(256);
    const dim3 gSta(32, 2, 8);    // M=256
    const dim3 gBr(32, 4, 8);     // M=512, K=256 partials
    const dim3 gC1(32, 8, 2);     // M=1024, batch pair
    const dim3 gCe(32, 4, 2);     // M=512, batch pair

    // ---- phase 1: rw branch (Y second half -> YS), PT/CV scratch in d_out tail
    gemm1x1<0, 1><<<gSta, blk, 0, stream>>>(x, w_sta, 512, b_sta, A, 256,
                                            nullptr, nullptr, 0, 512);
    gemm1x1<0, 0><<<gBr, blk, 0, stream>>>(A, w_cv2 + 0, 1024, b_cv2, YS, 512,
                                           nullptr, nullptr, 0, 256);
    rmax1<<<256, blk, 0, stream>>>(A, PT);
    rmax2<<<1, blk, 0, stream>>>(PT, CV + 0);
    pool_rw_fused<<<2048, blk, 0, stream>>>(A, CV + 0, B);
    gemm1x1<1, 0><<<gBr, blk, 0, stream>>>(B, w_cv2 + 256, 1024, nullptr, YS, 512,
                                           nullptr, nullptr, 0, 256);
    rmax1<<<256, blk, 0, stream>>>(B, PT);
    rmax2<<<1, blk, 0, stream>>>(PT, CV + 1);
    pool_rw_fused<<<2048, blk, 0, stream>>>(B, CV + 1, A);
    gemm1x1<1, 0><<<gBr, blk, 0, stream>>>(A, w_cv2 + 512, 1024, nullptr, YS, 512,
                                           nullptr, nullptr, 0, 256);
    rmax1<<<256, blk, 0, stream>>>(A, PT);
    rmax2<<<1, blk, 0, stream>>>(PT, CV + 2);
    pool_rw_fused<<<2048, blk, 0, stream>>>(A, CV + 2, B);
    gemm1x1<1, 1><<<gBr, blk, 0, stream>>>(B, w_cv2 + 768, 1024, nullptr, YS, 512,
                                           nullptr, nullptr, 0, 256);

    // ---- phase 2: tma branch (Y first half -> YF in d_out); recompute x_aux
    gemm1x1<0, 1><<<gSta, blk, 0, stream>>>(x, w_sta, 512, b_sta, A, 256,
                                            nullptr, nullptr, 0, 512);
    gemm1x1<0, 0><<<gBr, blk, 0, stream>>>(A, w_cv1 + 0, 1024, b_cv1, YF, 512,
                                           nullptr, nullptr, 0, 256);
    pool_tma_fused<<<2048, blk, 0, stream>>>(A, B);
    gemm1x1<1, 0><<<gBr, blk, 0, stream>>>(B, w_cv1 + 256, 1024, nullptr, YF, 512,
                                           nullptr, nullptr, 0, 256);
    pool_tma_fused<<<2048, blk, 0, stream>>>(B, A);
    gemm1x1<1, 0><<<gBr, blk, 0, stream>>>(A, w_cv1 + 512, 1024, nullptr, YF, 512,
                                           nullptr, nullptr, 0, 256);
    pool_tma_fused<<<2048, blk, 0, stream>>>(A, B);
    gemm1x1<1, 1><<<gBr, blk, 0, stream>>>(B, w_cv1 + 768, 1024, nullptr, YF, 512,
                                           nullptr, nullptr, 0, 256);

    // ---- phase 3: per batch-pair: dw chain -> a4 (A), gated c1 -> g (B),
    //      cvend -> d_out (overwrites YF rows of this pair only, after use)
    for (int b0 = 0; b0 < 8; b0 += 2) {
        lska_dw_pair<<<2048, blk, 0, stream>>>(YF, YS, b0,
                                               w_dwh, b_dwh, w_dwv, b_dwv,
                                               w_ddwh, b_ddwh, w_ddwv, b_ddwv, A);
        gemm1x1<0, 2><<<gC1, blk, 0, stream>>>(A, w_c1, 1024, b_c1, B, 1024,
                                               YF, YS, b0, 1024);
        gemm1x1<0, 1><<<gCe, blk, 0, stream>>>(B, w_cvend, 1024, b_cvend,
                                               out + (size_t)b0 * 2097152, 512,
                                               nullptr, nullptr, 0, 1024);
    }
}

// Round 4
// 1380.007 us; speedup vs baseline: 2.1500x; 2.1500x over previous
//
#include <hip/hip_runtime.h>
#include <math.h>

typedef __attribute__((ext_vector_type(8))) short short8;
typedef __attribute__((ext_vector_type(16))) float floatx16;

__device__ __forceinline__ float silu_f(float v) { return v / (1.0f + expf(-v)); }
__device__ __forceinline__ float bf2f(unsigned short u) {
    unsigned int x = ((unsigned int)u) << 16;
    return __uint_as_float(x);
}
__device__ __forceinline__ unsigned short f2bf(float f) {
    unsigned int u = __float_as_uint(f);
    u += 0x7FFFu + ((u >> 16) & 1u);
    return (unsigned short)(u >> 16);
}

struct BSlots { const unsigned short* p[4]; };

// ---------------- bf16 MFMA GEMM (1x1 conv):
// out[(z*OC+m)*4096+n] = EPI( sum_k (Ah+Al)[m][k] * B[k][n] + bias[m] )
// B given as 4 slot tensors of 256 channels each (bf16), batch stride bstride.
// EPI: 0 = SiLU -> bf16 store; 1 = gate-mult by Y2b -> bf16 store; 2 = SiLU -> f32
#define APITCH 36   // bf16 elems per A LDS row (32 data + 4 pad) -> conflict-free b64
#define BPITCH 18   // dwords per B LDS row (16 data + 2 pad), k-pairs packed per dword

template <int EPI>
__global__ __launch_bounds__(256, 2)
void gemm_mfma(const unsigned short* __restrict__ Ahp,
               const unsigned short* __restrict__ Alp, int ldK,
               BSlots bs, long bstride,
               const float* __restrict__ bias,
               void* __restrict__ outv, int OC,
               const unsigned short* __restrict__ gate, int b0, int K)
{
    __shared__ __align__(16) unsigned short As[2][128 * APITCH];
    __shared__ __align__(16) unsigned int   Bsm[256 * BPITCH];

    const int t  = threadIdx.x;
    const int z  = blockIdx.z;
    const int m0 = blockIdx.y * 128;
    const int n0 = blockIdx.x * 256;

    // staging ids
    const int am = t >> 1, ahf = t & 1;          // A: row, k-half (16 elems)
    const int bn = (t & 31) * 8, bkg = t >> 5;   // B: 8 n-cols, 4 k-rows group

    // compute ids
    const int w = t >> 6, lane = t & 63;
    const int wm = (w & 1) * 64, wn = (w >> 1) * 128;
    const int lm = lane & 31, q = lane >> 5;

    floatx16 acc[2][4];
#pragma unroll
    for (int i = 0; i < 2; ++i)
#pragma unroll
        for (int j = 0; j < 4; ++j)
#pragma unroll
            for (int r = 0; r < 16; ++r) acc[i][j][r] = 0.0f;

    const unsigned short* Aph = Ahp + (size_t)(m0 + am) * ldK + ahf * 16;
    const unsigned short* Apl = Alp + (size_t)(m0 + am) * ldK + ahf * 16;

    for (int k0 = 0; k0 < K; k0 += 32) {
        // ---- global loads
        uint4 ah0 = *(const uint4*)(Aph + k0);
        uint4 ah1 = *(const uint4*)(Aph + k0 + 8);
        uint4 al0 = *(const uint4*)(Apl + k0);
        uint4 al1 = *(const uint4*)(Apl + k0 + 8);
        const int slot = k0 >> 8;
        const unsigned short* Bp = bs.p[slot] + (size_t)z * bstride
                                 + (size_t)((k0 & 255) + bkg * 4) * 4096 + n0 + bn;
        uint4 r0 = *(const uint4*)(Bp);
        uint4 r1 = *(const uint4*)(Bp + 4096);
        uint4 r2 = *(const uint4*)(Bp + 8192);
        uint4 r3 = *(const uint4*)(Bp + 12288);

        __syncthreads();   // previous iteration's frag reads done

        // ---- A tile: [m][k] bf16, pitch 36
        {
            unsigned short* Ad0 = &As[0][am * APITCH + ahf * 16];
            unsigned short* Ad1 = &As[1][am * APITCH + ahf * 16];
            ((uint2*)Ad0)[0] = *((const uint2*)&ah0);
            ((uint2*)Ad0)[1] = *((const uint2*)&ah0 + 1);
            ((uint2*)Ad0)[2] = *((const uint2*)&ah1);
            ((uint2*)Ad0)[3] = *((const uint2*)&ah1 + 1);
            ((uint2*)Ad1)[0] = *((const uint2*)&al0);
            ((uint2*)Ad1)[1] = *((const uint2*)&al0 + 1);
            ((uint2*)Ad1)[2] = *((const uint2*)&al1);
            ((uint2*)Ad1)[3] = *((const uint2*)&al1 + 1);
        }
        // ---- B tile: transposed [n][k-pair dwords], pitch 18 dwords
        {
            const unsigned int* d0 = (const unsigned int*)&r0;
            const unsigned int* d1 = (const unsigned int*)&r1;
            const unsigned int* d2 = (const unsigned int*)&r2;
            const unsigned int* d3 = (const unsigned int*)&r3;
#pragma unroll
            for (int ii = 0; ii < 8; ++ii) {
                int i = (ii + (t & 7)) & 7;   // rotate to spread write banks
                unsigned int sel = (i & 1) ? 0x07060302u : 0x05040100u;
                uint2 pv;
                pv.x = __builtin_amdgcn_perm(d1[i >> 1], d0[i >> 1], sel);
                pv.y = __builtin_amdgcn_perm(d3[i >> 1], d2[i >> 1], sel);
                *(uint2*)&Bsm[(bn + i) * BPITCH + bkg * 2] = pv;
            }
        }
        __syncthreads();

        // ---- compute: 2 k-steps x (2 m-tiles x 4 n-tiles) x (hi+lo)
#pragma unroll
        for (int s = 0; s < 2; ++s) {
            union { short8 v; uint2 u[2]; } afh[2], afl[2], bfr[4];
#pragma unroll
            for (int i = 0; i < 2; ++i) {
                int rb = (wm + 32 * i + lm) * APITCH + s * 16 + q * 8;
                afh[i].u[0] = *(const uint2*)&As[0][rb];
                afh[i].u[1] = *(const uint2*)&As[0][rb + 4];
                afl[i].u[0] = *(const uint2*)&As[1][rb];
                afl[i].u[1] = *(const uint2*)&As[1][rb + 4];
            }
#pragma unroll
            for (int j = 0; j < 4; ++j) {
                int nb = (wn + 32 * j + lm) * BPITCH + s * 8 + q * 4;
                bfr[j].u[0] = *(const uint2*)&Bsm[nb];
                bfr[j].u[1] = *(const uint2*)&Bsm[nb + 2];
            }
#pragma unroll
            for (int i = 0; i < 2; ++i)
#pragma unroll
                for (int j = 0; j < 4; ++j) {
                    acc[i][j] = __builtin_amdgcn_mfma_f32_32x32x16_bf16(
                        afh[i].v, bfr[j].v, acc[i][j], 0, 0, 0);
                    acc[i][j] = __builtin_amdgcn_mfma_f32_32x32x16_bf16(
                        afl[i].v, bfr[j].v, acc[i][j], 0, 0, 0);
                }
        }
    }

    // ---- epilogue; C/D: col=lane&31, row=(reg&3)+8*(reg>>2)+4*(lane>>5)
#pragma unroll
    for (int i = 0; i < 2; ++i)
#pragma unroll
        for (int j = 0; j < 4; ++j)
#pragma unroll
            for (int r = 0; r < 16; ++r) {
                int row = wm + 32 * i + (r & 3) + 8 * (r >> 2) + 4 * q;
                int col = n0 + wn + 32 * j + lm;
                int mg  = m0 + row;
                size_t ob = ((size_t)z * OC + mg) * 4096 + col;
                float v = acc[i][j][r] + bias[mg];
                if (EPI == 0) {
                    ((unsigned short*)outv)[ob] = f2bf(silu_f(v));
                } else if (EPI == 1) {
                    float g = bf2f(gate[((size_t)(b0 + z) * 1024 + mg) * 4096 + col]);
                    ((unsigned short*)outv)[ob] = f2bf(v * g);
                } else {
                    ((float*)outv)[ob] = silu_f(v);
                }
            }
}

// ---------------- fused separable 5x5 TMaxAvg pool, bf16 io, block = one plane
__global__ __launch_bounds__(256)
void pool_tma_b(const unsigned short* __restrict__ in, unsigned short* __restrict__ out)
{
    __shared__ float xs[4096], hm[4096], hs[4096];
    const size_t base = (size_t)blockIdx.x * 4096;
    const int t = threadIdx.x;
    for (int i = t; i < 4096; i += 256) xs[i] = bf2f(in[base + i]);
    __syncthreads();
    for (int i = t; i < 4096; i += 256) {
        int x = i & 63;
        float mx = -INFINITY, sm = 0.0f;
#pragma unroll
        for (int dx = -2; dx <= 2; ++dx) {
            int xx = x + dx;
            if (0 <= xx && xx < 64) { float v = xs[i + dx]; mx = fmaxf(mx, v); sm += v; }
        }
        hm[i] = mx; hs[i] = sm;
    }
    __syncthreads();
    for (int i = t; i < 4096; i += 256) {
        int y = i >> 6;
        float mx = -INFINITY, sm = 0.0f;
#pragma unroll
        for (int dy = -2; dy <= 2; ++dy) {
            int yy = y + dy;
            if (0 <= yy && yy < 64) { mx = fmaxf(mx, hm[i + dy * 64]); sm += hs[i + dy * 64]; }
        }
        out[base + i] = f2bf(0.9f * mx + 0.1f * (sm * (1.0f / 25.0f)));
    }
}

// ---------------- fused separable 5x5 RW pool, bf16 io, shift c dropped (cancels)
__global__ __launch_bounds__(256)
void pool_rw_b(const unsigned short* __restrict__ in, unsigned short* __restrict__ out)
{
    __shared__ float xs[4096], hx[4096], he[4096];
    const size_t base = (size_t)blockIdx.x * 4096;
    const int t = threadIdx.x;
    for (int i = t; i < 4096; i += 256) xs[i] = bf2f(in[base + i]);
    __syncthreads();
    for (int i = t; i < 4096; i += 256) {
        int x = i & 63;
        float se = 0.0f, sx = 0.0f;
#pragma unroll
        for (int dx = -2; dx <= 2; ++dx) {
            int xx = x + dx;
            if (0 <= xx && xx < 64) {
                float v = xs[i + dx];
                float e = expf(v);
                se += e; sx += e * v;
            }
        }
        hx[i] = sx; he[i] = se;
    }
    __syncthreads();
    for (int i = t; i < 4096; i += 256) {
        int y = i >> 6;
        float se = 0.0f, sx = 0.0f;
#pragma unroll
        for (int dy = -2; dy <= 2; ++dy) {
            int yy = y + dy;
            if (0 <= yy && yy < 64) { sx += hx[i + dy * 64]; se += he[i + dy * 64]; }
        }
        out[base + i] = f2bf(sx / (se + 1e-6f));
    }
}

// ---------------- fused LSKA depthwise chain for a batch-QUAD, bf16 io
__global__ __launch_bounds__(256)
void lska_dw_quad(const unsigned short* __restrict__ Y2b, int b0,
                  const float* __restrict__ wh1, const float* __restrict__ bh1,
                  const float* __restrict__ wv1, const float* __restrict__ bv1,
                  const float* __restrict__ wh2, const float* __restrict__ bh2,
                  const float* __restrict__ wv2, const float* __restrict__ bv2,
                  unsigned short* __restrict__ outq)
{
    __shared__ float buf0[4096], buf1[4096];
    const int bi = blockIdx.x;
    const int zz = bi >> 10, c = bi & 1023;
    const unsigned short* src = Y2b + ((size_t)(b0 + zz) * 1024 + c) * 4096;
    unsigned short* dst = outq + (size_t)bi * 4096;
    const int t = threadIdx.x;
    for (int i = t; i < 4096; i += 256) buf0[i] = bf2f(src[i]);
    __syncthreads();
    {
        float w0 = wh1[c * 3], w1 = wh1[c * 3 + 1], w2 = wh1[c * 3 + 2], bb = bh1[c];
        for (int i = t; i < 4096; i += 256) {
            int x = i & 63;
            float a = fmaf(w1, buf0[i], bb);
            if (x >= 1)  a = fmaf(w0, buf0[i - 1], a);
            if (x <= 62) a = fmaf(w2, buf0[i + 1], a);
            buf1[i] = a;
        }
    }
    __syncthreads();
    {
        float w0 = wv1[c * 3], w1 = wv1[c * 3 + 1], w2 = wv1[c * 3 + 2], bb = bv1[c];
        for (int i = t; i < 4096; i += 256) {
            int y = i >> 6;
            float a = fmaf(w1, buf1[i], bb);
            if (y >= 1)  a = fmaf(w0, buf1[i - 64], a);
            if (y <= 62) a = fmaf(w2, buf1[i + 64], a);
            buf0[i] = a;
        }
    }
    __syncthreads();
    {
        float w0 = wh2[c * 3], w1 = wh2[c * 3 + 1], w2 = wh2[c * 3 + 2], bb = bh2[c];
        for (int i = t; i < 4096; i += 256) {
            int x = i & 63;
            float a = fmaf(w1, buf0[i], bb);
            if (x >= 2)  a = fmaf(w0, buf0[i - 2], a);
            if (x <= 61) a = fmaf(w2, buf0[i + 2], a);
            buf1[i] = a;
        }
    }
    __syncthreads();
    {
        float w0 = wv2[c * 3], w1 = wv2[c * 3 + 1], w2 = wv2[c * 3 + 2], bb = bv2[c];
        for (int i = t; i < 4096; i += 256) {
            int y = i >> 6;
            float a = fmaf(w1, buf1[i], bb);
            if (y >= 2)  a = fmaf(w0, buf1[i - 128], a);
            if (y <= 61) a = fmaf(w2, buf1[i + 128], a);
            dst[i] = f2bf(a);
        }
    }
}

// ---------------- conversions
__global__ void f2bf_vec(const float* __restrict__ in, unsigned short* __restrict__ out)
{
    size_t i = ((size_t)blockIdx.x * 256 + threadIdx.x) * 8;
    float4 v0 = *(const float4*)(in + i);
    float4 v1 = *(const float4*)(in + i + 4);
    uint2 o0, o1;
    o0.x = (unsigned)f2bf(v0.x) | ((unsigned)f2bf(v0.y) << 16);
    o0.y = (unsigned)f2bf(v0.z) | ((unsigned)f2bf(v0.w) << 16);
    o1.x = (unsigned)f2bf(v1.x) | ((unsigned)f2bf(v1.y) << 16);
    o1.y = (unsigned)f2bf(v1.z) | ((unsigned)f2bf(v1.w) << 16);
    *(uint2*)(out + i) = o0;
    *(uint2*)(out + i + 4) = o1;
}

__global__ void wsplit(const float* __restrict__ w, unsigned short* __restrict__ wh,
                       unsigned short* __restrict__ wl)
{
    int i = blockIdx.x * 256 + threadIdx.x;
    float v = w[i];
    unsigned short h = f2bf(v);
    wh[i] = h;
    wl[i] = f2bf(v - bf2f(h));
}

extern "C" void kernel_launch(void* const* d_in, const int* in_sizes, int n_in,
                              void* d_out, int out_size, void* d_ws, size_t ws_size,
                              hipStream_t stream)
{
    const float* x       = (const float*)d_in[0];
    const float* w_sta   = (const float*)d_in[1];
    const float* b_sta   = (const float*)d_in[2];
    const float* w_cv1   = (const float*)d_in[3];
    const float* b_cv1   = (const float*)d_in[4];
    const float* w_cv2   = (const float*)d_in[5];
    const float* b_cv2   = (const float*)d_in[6];
    const float* w_cvend = (const float*)d_in[7];
    const float* b_cvend = (const float*)d_in[8];
    const float* w_dwh   = (const float*)d_in[9];
    const float* b_dwh   = (const float*)d_in[10];
    const float* w_dwv   = (const float*)d_in[11];
    const float* b_dwv   = (const float*)d_in[12];
    const float* w_ddwh  = (const float*)d_in[13];
    const float* b_ddwh  = (const float*)d_in[14];
    const float* w_ddwv  = (const float*)d_in[15];
    const float* b_ddwv  = (const float*)d_in[16];
    const float* w_c1    = (const float*)d_in[17];
    const float* b_c1    = (const float*)d_in[18];
    float* outf = (float*)d_out;
    unsigned short* Y2b = (unsigned short*)d_out;   // [8,1024,4096] bf16, = 67.1 MB

    // ws (bf16 element offsets), total used 111.7 MB <= 128 MiB:
    unsigned short* WS    = (unsigned short*)d_ws;
    unsigned short* xb    = WS;                  // [8,512,4096]  16,777,216 elems
    unsigned short* xaux  = WS + 16777216;       // [8,256,4096]   8,388,608
    unsigned short* pA    = WS + 25165824;       //                8,388,608
    unsigned short* pB    = WS + 33554432;
    unsigned short* pC    = WS + 41943040;
    unsigned short* WT    = WS + 50331648;       // weights hi/lo, 5,505,024
    unsigned short* a4q   = WS;                  // phase B: [4,1024,4096] (reuse xb)
    unsigned short* gq    = WS + 16777216;       // phase B: [4,1024,4096] (reuse xaux+pA)

    unsigned short* sta_h = WT,           * sta_l = WT + 131072;
    unsigned short* cv1_h = WT + 262144,  * cv1_l = WT + 786432;
    unsigned short* cv2_h = WT + 1310720, * cv2_l = WT + 1835008;
    unsigned short* c1_h  = WT + 2359296, * c1_l  = WT + 3407872;
    unsigned short* cve_h = WT + 4456448, * cve_l = WT + 4980736;

    dim3 blk(256);

    // 0) conversions
    f2bf_vec<<<8192, blk, 0, stream>>>(x, xb);
    wsplit<<<512,  blk, 0, stream>>>(w_sta,   sta_h, sta_l);
    wsplit<<<2048, blk, 0, stream>>>(w_cv1,   cv1_h, cv1_l);
    wsplit<<<2048, blk, 0, stream>>>(w_cv2,   cv2_h, cv2_l);
    wsplit<<<4096, blk, 0, stream>>>(w_c1,    c1_h,  c1_l);
    wsplit<<<2048, blk, 0, stream>>>(w_cvend, cve_h, cve_l);

    // 1) x_aux = SiLU(sta(x)) -> bf16 [8,256,4096]
    {
        BSlots s; s.p[0] = xb; s.p[1] = xb + 1048576; s.p[2] = xb; s.p[3] = xb;
        gemm_mfma<0><<<dim3(16, 2, 8), blk, 0, stream>>>(
            sta_h, sta_l, 512, s, 2097152L, b_sta, xaux, 256, nullptr, 0, 512);
    }

    // 2) RW branch -> pA,pB,pC ; cv2 -> Y2b channels 512..1023
    pool_rw_b<<<2048, blk, 0, stream>>>(xaux, pA);
    pool_rw_b<<<2048, blk, 0, stream>>>(pA, pB);
    pool_rw_b<<<2048, blk, 0, stream>>>(pB, pC);
    {
        BSlots s; s.p[0] = xaux; s.p[1] = pA; s.p[2] = pB; s.p[3] = pC;
        gemm_mfma<0><<<dim3(16, 4, 8), blk, 0, stream>>>(
            cv2_h, cv2_l, 1024, s, 1048576L, b_cv2, Y2b + 512 * 4096, 1024,
            nullptr, 0, 1024);
    }

    // 3) TMaxAvg branch -> pA,pB,pC ; cv1 -> Y2b channels 0..511
    pool_tma_b<<<2048, blk, 0, stream>>>(xaux, pA);
    pool_tma_b<<<2048, blk, 0, stream>>>(pA, pB);
    pool_tma_b<<<2048, blk, 0, stream>>>(pB, pC);
    {
        BSlots s; s.p[0] = xaux; s.p[1] = pA; s.p[2] = pB; s.p[3] = pC;
        gemm_mfma<0><<<dim3(16, 4, 8), blk, 0, stream>>>(
            cv1_h, cv1_l, 1024, s, 1048576L, b_cv1, Y2b, 1024, nullptr, 0, 1024);
    }

    // 4) per batch-quad: dw chain -> a4q ; gated c1 -> gq ; cvend -> d_out
    //    (cvend quad writes overwrite exactly its own, already-consumed Y2b rows)
    for (int qd = 0; qd < 2; ++qd) {
        const int b0 = 4 * qd;
        lska_dw_quad<<<4096, blk, 0, stream>>>(Y2b, b0,
                                               w_dwh, b_dwh, w_dwv, b_dwv,
                                               w_ddwh, b_ddwh, w_ddwv, b_ddwv, a4q);
        {
            BSlots s; s.p[0] = a4q; s.p[1] = a4q + 1048576;
            s.p[2] = a4q + 2097152; s.p[3] = a4q + 3145728;
            gemm_mfma<1><<<dim3(16, 8, 4), blk, 0, stream>>>(
                c1_h, c1_l, 1024, s, 4194304L, b_c1, gq, 1024, Y2b, b0, 1024);
        }
        {
            BSlots s; s.p[0] = gq; s.p[1] = gq + 1048576;
            s.p[2] = gq + 2097152; s.p[3] = gq + 3145728;
            gemm_mfma<2><<<dim3(16, 4, 4), blk, 0, stream>>>(
                cve_h, cve_l, 1024, s, 4194304L, b_cvend,
                outf + (size_t)b0 * 2097152, 512, nullptr, 0, 1024);
        }
    }
}

// Round 5
// 947.954 us; speedup vs baseline: 3.1299x; 1.4558x over previous
//
#include <hip/hip_runtime.h>
#include <math.h>

typedef __attribute__((ext_vector_type(8))) short short8;
typedef __attribute__((ext_vector_type(16))) float floatx16;

__device__ __forceinline__ float silu_f(float v) { return v / (1.0f + expf(-v)); }
__device__ __forceinline__ float bf2f(unsigned short u) {
    unsigned int x = ((unsigned int)u) << 16;
    return __uint_as_float(x);
}
__device__ __forceinline__ unsigned short f2bf(float f) {
    unsigned int u = __float_as_uint(f);
    u += 0x7FFFu + ((u >> 16) & 1u);
    return (unsigned short)(u >> 16);
}

struct BSlots { const unsigned short* p[4]; };

// ---------------- bf16 MFMA GEMM (1x1 conv), software-prefetched:
// out[(z*OC+m)*4096+n] = EPI( sum_k (Ah+Al)[m][k] * B[k][n] + bias[m] )
// Dual-branch: if Ahp2 != null and m0>=512, use (Ahp2,Alp2,bias2,bs2) with
// branch-local row mA = m0-512 (merged cv1/cv2 dispatch).
// EPI: 0 = SiLU -> bf16; 1 = gate-mult by Y2b -> bf16; 2 = SiLU -> f32
#define APITCH 36   // bf16 elems per A LDS row (32 data + 4 pad)
#define BPITCH 18   // dwords per B LDS row (16 data + 2 pad), k-pairs per dword

template <int EPI>
__global__ __launch_bounds__(256, 2)
void gemm_mfma(const unsigned short* __restrict__ Ahp,
               const unsigned short* __restrict__ Alp,
               const unsigned short* __restrict__ Ahp2,
               const unsigned short* __restrict__ Alp2, int ldK,
               BSlots bs, BSlots bs2, long bstride,
               const float* __restrict__ bias, const float* __restrict__ bias2,
               void* __restrict__ outv, int OC,
               const unsigned short* __restrict__ gate, int b0, int K)
{
    __shared__ __align__(16) unsigned short As[2][128 * APITCH];
    __shared__ __align__(16) unsigned int   Bsm[256 * BPITCH];

    const int t  = threadIdx.x;
    const int z  = blockIdx.z;
    const int m0 = blockIdx.y * 128;
    const int n0 = blockIdx.x * 256;

    int mA = m0;
    if (Ahp2 != nullptr && m0 >= 512) {
        Ahp = Ahp2; Alp = Alp2; bias = bias2; bs = bs2; mA = m0 - 512;
    }

    // staging ids
    const int am = t >> 1, ahf = t & 1;          // A: row, k-half (16 elems)
    const int bkg = t & 7, bn8 = t >> 3;         // B: k-group (4 rows), n-octet

    // compute ids
    const int w = t >> 6, lane = t & 63;
    const int wm = (w & 1) * 64, wn = (w >> 1) * 128;
    const int lm = lane & 31, q = lane >> 5;

    floatx16 acc[2][4];
#pragma unroll
    for (int i = 0; i < 2; ++i)
#pragma unroll
        for (int j = 0; j < 4; ++j)
#pragma unroll
            for (int r = 0; r < 16; ++r) acc[i][j][r] = 0.0f;

    const unsigned short* Aph = Ahp + (size_t)(mA + am) * ldK + ahf * 16;
    const unsigned short* Apl = Alp + (size_t)(mA + am) * ldK + ahf * 16;

    uint4 ah0, ah1, al0, al1, r0, r1, r2, r3;
    // ---- prefetch tile 0
    {
        ah0 = *(const uint4*)(Aph);
        ah1 = *(const uint4*)(Aph + 8);
        al0 = *(const uint4*)(Apl);
        al1 = *(const uint4*)(Apl + 8);
        const unsigned short* Bp = bs.p[0] + (size_t)z * bstride
                                 + (size_t)(bkg * 4) * 4096 + n0 + bn8 * 8;
        r0 = *(const uint4*)(Bp);
        r1 = *(const uint4*)(Bp + 4096);
        r2 = *(const uint4*)(Bp + 8192);
        r3 = *(const uint4*)(Bp + 12288);
    }

    for (int k0 = 0; k0 < K; k0 += 32) {
        __syncthreads();   // previous iteration's frag reads done

        // ---- stage A tile: [m][k] bf16, pitch 36 (conflict-minimal)
        {
            unsigned short* Ad0 = &As[0][am * APITCH + ahf * 16];
            unsigned short* Ad1 = &As[1][am * APITCH + ahf * 16];
            ((uint2*)Ad0)[0] = *((const uint2*)&ah0);
            ((uint2*)Ad0)[1] = *((const uint2*)&ah0 + 1);
            ((uint2*)Ad0)[2] = *((const uint2*)&ah1);
            ((uint2*)Ad0)[3] = *((const uint2*)&ah1 + 1);
            ((uint2*)Ad1)[0] = *((const uint2*)&al0);
            ((uint2*)Ad1)[1] = *((const uint2*)&al0 + 1);
            ((uint2*)Ad1)[2] = *((const uint2*)&al1);
            ((uint2*)Ad1)[3] = *((const uint2*)&al1 + 1);
        }
        // ---- stage B tile: transposed [n][k-pair dwords], pitch 18 dwords.
        // store banks: 16*(bn8&1) + 18*i + 2*bkg -> 16 bank-pairs x 4 lanes = min
        {
            const unsigned int* d0 = (const unsigned int*)&r0;
            const unsigned int* d1 = (const unsigned int*)&r1;
            const unsigned int* d2 = (const unsigned int*)&r2;
            const unsigned int* d3 = (const unsigned int*)&r3;
#pragma unroll
            for (int i = 0; i < 8; ++i) {
                unsigned int sel = (i & 1) ? 0x07060302u : 0x05040100u;
                uint2 pv;
                pv.x = __builtin_amdgcn_perm(d1[i >> 1], d0[i >> 1], sel);
                pv.y = __builtin_amdgcn_perm(d3[i >> 1], d2[i >> 1], sel);
                *(uint2*)&Bsm[(bn8 * 8 + i) * BPITCH + bkg * 2] = pv;
            }
        }
        __syncthreads();

        // ---- issue prefetch for next tile (covered by compute below)
        const int k1 = k0 + 32;
        if (k1 < K) {
            ah0 = *(const uint4*)(Aph + k1);
            ah1 = *(const uint4*)(Aph + k1 + 8);
            al0 = *(const uint4*)(Apl + k1);
            al1 = *(const uint4*)(Apl + k1 + 8);
            const unsigned short* Bp = bs.p[k1 >> 8] + (size_t)z * bstride
                                     + (size_t)((k1 & 255) + bkg * 4) * 4096
                                     + n0 + bn8 * 8;
            r0 = *(const uint4*)(Bp);
            r1 = *(const uint4*)(Bp + 4096);
            r2 = *(const uint4*)(Bp + 8192);
            r3 = *(const uint4*)(Bp + 12288);
        }

        // ---- compute: 2 k-steps x (2 m-tiles x 4 n-tiles) x (hi+lo)
#pragma unroll
        for (int s = 0; s < 2; ++s) {
            union { short8 v; uint2 u[2]; } afh[2], afl[2], bfr[4];
#pragma unroll
            for (int i = 0; i < 2; ++i) {
                int rb = (wm + 32 * i + lm) * APITCH + s * 16 + q * 8;
                afh[i].u[0] = *(const uint2*)&As[0][rb];
                afh[i].u[1] = *(const uint2*)&As[0][rb + 4];
                afl[i].u[0] = *(const uint2*)&As[1][rb];
                afl[i].u[1] = *(const uint2*)&As[1][rb + 4];
            }
#pragma unroll
            for (int j = 0; j < 4; ++j) {
                int nb = (wn + 32 * j + lm) * BPITCH + s * 8 + q * 4;
                bfr[j].u[0] = *(const uint2*)&Bsm[nb];
                bfr[j].u[1] = *(const uint2*)&Bsm[nb + 2];
            }
#pragma unroll
            for (int i = 0; i < 2; ++i)
#pragma unroll
                for (int j = 0; j < 4; ++j) {
                    acc[i][j] = __builtin_amdgcn_mfma_f32_32x32x16_bf16(
                        afh[i].v, bfr[j].v, acc[i][j], 0, 0, 0);
                    acc[i][j] = __builtin_amdgcn_mfma_f32_32x32x16_bf16(
                        afl[i].v, bfr[j].v, acc[i][j], 0, 0, 0);
                }
        }
    }

    // ---- epilogue; C/D: col=lane&31, row=(reg&3)+8*(reg>>2)+4*(lane>>5)
#pragma unroll
    for (int i = 0; i < 2; ++i)
#pragma unroll
        for (int j = 0; j < 4; ++j)
#pragma unroll
            for (int r = 0; r < 16; ++r) {
                int row = wm + 32 * i + (r & 3) + 8 * (r >> 2) + 4 * q;
                int col = n0 + wn + 32 * j + lm;
                int mg  = m0 + row;
                size_t ob = ((size_t)z * OC + mg) * 4096 + col;
                float v = acc[i][j][r] + bias[mA + row];
                if (EPI == 0) {
                    ((unsigned short*)outv)[ob] = f2bf(silu_f(v));
                } else if (EPI == 1) {
                    float g = bf2f(gate[((size_t)(b0 + z) * 1024 + mg) * 4096 + col]);
                    ((unsigned short*)outv)[ob] = f2bf(v * g);
                } else {
                    ((float*)outv)[ob] = silu_f(v);
                }
            }
}

// ---------------- fused separable 5x5 TMaxAvg pool, bf16 io, block = one plane
__global__ __launch_bounds__(256)
void pool_tma_b(const unsigned short* __restrict__ in, unsigned short* __restrict__ out)
{
    __shared__ float xs[4096], hm[4096], hs[4096];
    const size_t base = (size_t)blockIdx.x * 4096;
    const int t = threadIdx.x;
    for (int i = t; i < 4096; i += 256) xs[i] = bf2f(in[base + i]);
    __syncthreads();
    for (int i = t; i < 4096; i += 256) {
        int x = i & 63;
        float mx = -INFINITY, sm = 0.0f;
#pragma unroll
        for (int dx = -2; dx <= 2; ++dx) {
            int xx = x + dx;
            if (0 <= xx && xx < 64) { float v = xs[i + dx]; mx = fmaxf(mx, v); sm += v; }
        }
        hm[i] = mx; hs[i] = sm;
    }
    __syncthreads();
    for (int i = t; i < 4096; i += 256) {
        int y = i >> 6;
        float mx = -INFINITY, sm = 0.0f;
#pragma unroll
        for (int dy = -2; dy <= 2; ++dy) {
            int yy = y + dy;
            if (0 <= yy && yy < 64) { mx = fmaxf(mx, hm[i + dy * 64]); sm += hs[i + dy * 64]; }
        }
        out[base + i] = f2bf(0.9f * mx + 0.1f * (sm * (1.0f / 25.0f)));
    }
}

// ---------------- fused separable 5x5 RW pool, bf16 io (global shift cancels)
__global__ __launch_bounds__(256)
void pool_rw_b(const unsigned short* __restrict__ in, unsigned short* __restrict__ out)
{
    __shared__ float xs[4096], hx[4096], he[4096];
    const size_t base = (size_t)blockIdx.x * 4096;
    const int t = threadIdx.x;
    for (int i = t; i < 4096; i += 256) xs[i] = bf2f(in[base + i]);
    __syncthreads();
    for (int i = t; i < 4096; i += 256) {
        int x = i & 63;
        float se = 0.0f, sx = 0.0f;
#pragma unroll
        for (int dx = -2; dx <= 2; ++dx) {
            int xx = x + dx;
            if (0 <= xx && xx < 64) {
                float v = xs[i + dx];
                float e = expf(v);
                se += e; sx += e * v;
            }
        }
        hx[i] = sx; he[i] = se;
    }
    __syncthreads();
    for (int i = t; i < 4096; i += 256) {
        int y = i >> 6;
        float se = 0.0f, sx = 0.0f;
#pragma unroll
        for (int dy = -2; dy <= 2; ++dy) {
            int yy = y + dy;
            if (0 <= yy && yy < 64) { sx += hx[i + dy * 64]; se += he[i + dy * 64]; }
        }
        out[base + i] = f2bf(sx / (se + 1e-6f));
    }
}

// ---------------- fused LSKA depthwise chain for a batch-QUAD, bf16 io
__global__ __launch_bounds__(256)
void lska_dw_quad(const unsigned short* __restrict__ Y2b, int b0,
                  const float* __restrict__ wh1, const float* __restrict__ bh1,
                  const float* __restrict__ wv1, const float* __restrict__ bv1,
                  const float* __restrict__ wh2, const float* __restrict__ bh2,
                  const float* __restrict__ wv2, const float* __restrict__ bv2,
                  unsigned short* __restrict__ outq)
{
    __shared__ float buf0[4096], buf1[4096];
    const int bi = blockIdx.x;
    const int zz = bi >> 10, c = bi & 1023;
    const unsigned short* src = Y2b + ((size_t)(b0 + zz) * 1024 + c) * 4096;
    unsigned short* dst = outq + (size_t)bi * 4096;
    const int t = threadIdx.x;
    for (int i = t; i < 4096; i += 256) buf0[i] = bf2f(src[i]);
    __syncthreads();
    {
        float w0 = wh1[c * 3], w1 = wh1[c * 3 + 1], w2 = wh1[c * 3 + 2], bb = bh1[c];
        for (int i = t; i < 4096; i += 256) {
            int x = i & 63;
            float a = fmaf(w1, buf0[i], bb);
            if (x >= 1)  a = fmaf(w0, buf0[i - 1], a);
            if (x <= 62) a = fmaf(w2, buf0[i + 1], a);
            buf1[i] = a;
        }
    }
    __syncthreads();
    {
        float w0 = wv1[c * 3], w1 = wv1[c * 3 + 1], w2 = wv1[c * 3 + 2], bb = bv1[c];
        for (int i = t; i < 4096; i += 256) {
            int y = i >> 6;
            float a = fmaf(w1, buf1[i], bb);
            if (y >= 1)  a = fmaf(w0, buf1[i - 64], a);
            if (y <= 62) a = fmaf(w2, buf1[i + 64], a);
            buf0[i] = a;
        }
    }
    __syncthreads();
    {
        float w0 = wh2[c * 3], w1 = wh2[c * 3 + 1], w2 = wh2[c * 3 + 2], bb = bh2[c];
        for (int i = t; i < 4096; i += 256) {
            int x = i & 63;
            float a = fmaf(w1, buf0[i], bb);
            if (x >= 2)  a = fmaf(w0, buf0[i - 2], a);
            if (x <= 61) a = fmaf(w2, buf0[i + 2], a);
            buf1[i] = a;
        }
    }
    __syncthreads();
    {
        float w0 = wv2[c * 3], w1 = wv2[c * 3 + 1], w2 = wv2[c * 3 + 2], bb = bv2[c];
        for (int i = t; i < 4096; i += 256) {
            int y = i >> 6;
            float a = fmaf(w1, buf1[i], bb);
            if (y >= 2)  a = fmaf(w0, buf1[i - 128], a);
            if (y <= 61) a = fmaf(w2, buf1[i + 128], a);
            dst[i] = f2bf(a);
        }
    }
}

// ---------------- conversions
__global__ void f2bf_vec(const float* __restrict__ in, unsigned short* __restrict__ out)
{
    size_t i = ((size_t)blockIdx.x * 256 + threadIdx.x) * 8;
    float4 v0 = *(const float4*)(in + i);
    float4 v1 = *(const float4*)(in + i + 4);
    uint2 o0, o1;
    o0.x = (unsigned)f2bf(v0.x) | ((unsigned)f2bf(v0.y) << 16);
    o0.y = (unsigned)f2bf(v0.z) | ((unsigned)f2bf(v0.w) << 16);
    o1.x = (unsigned)f2bf(v1.x) | ((unsigned)f2bf(v1.y) << 16);
    o1.y = (unsigned)f2bf(v1.z) | ((unsigned)f2bf(v1.w) << 16);
    *(uint2*)(out + i) = o0;
    *(uint2*)(out + i + 4) = o1;
}

__global__ void wsplit(const float* __restrict__ w, unsigned short* __restrict__ wh,
                       unsigned short* __restrict__ wl)
{
    int i = blockIdx.x * 256 + threadIdx.x;
    float v = w[i];
    unsigned short h = f2bf(v);
    wh[i] = h;
    wl[i] = f2bf(v - bf2f(h));
}

extern "C" void kernel_launch(void* const* d_in, const int* in_sizes, int n_in,
                              void* d_out, int out_size, void* d_ws, size_t ws_size,
                              hipStream_t stream)
{
    const float* x       = (const float*)d_in[0];
    const float* w_sta   = (const float*)d_in[1];
    const float* b_sta   = (const float*)d_in[2];
    const float* w_cv1   = (const float*)d_in[3];
    const float* b_cv1   = (const float*)d_in[4];
    const float* w_cv2   = (const float*)d_in[5];
    const float* b_cv2   = (const float*)d_in[6];
    const float* w_cvend = (const float*)d_in[7];
    const float* b_cvend = (const float*)d_in[8];
    const float* w_dwh   = (const float*)d_in[9];
    const float* b_dwh   = (const float*)d_in[10];
    const float* w_dwv   = (const float*)d_in[11];
    const float* b_dwv   = (const float*)d_in[12];
    const float* w_ddwh  = (const float*)d_in[13];
    const float* b_ddwh  = (const float*)d_in[14];
    const float* w_ddwv  = (const float*)d_in[15];
    const float* b_ddwv  = (const float*)d_in[16];
    const float* w_c1    = (const float*)d_in[17];
    const float* b_c1    = (const float*)d_in[18];
    float* outf = (float*)d_out;
    unsigned short* Y2b = (unsigned short*)d_out;   // [8,1024,4096] bf16 = 67.1 MB

    // ws (bf16 element offsets), total 128.45 MB <= 128 MiB:
    //   xaux, t1..t3 (tma stages), r1..r3 (rw stages): 7 x 8,388,608 shorts
    //   WT weights hi/lo: 5,505,024 shorts
    // Overlays: xb (input bf16, 16.7M shorts) = t1..t2 (dead until pools run);
    //   phase-4: a4q = xaux+t1, gq = t2+t3 (pools dead then).
    unsigned short* WS   = (unsigned short*)d_ws;
    unsigned short* xaux = WS;
    unsigned short* t1   = WS + 8388608;
    unsigned short* t2   = WS + 16777216;
    unsigned short* t3   = WS + 25165824;
    unsigned short* r1   = WS + 33554432;
    unsigned short* r2   = WS + 41943040;
    unsigned short* r3   = WS + 50331648;
    unsigned short* WT   = WS + 58720256;
    unsigned short* xb   = t1;
    unsigned short* a4q  = WS;
    unsigned short* gq   = WS + 16777216;

    unsigned short* sta_h = WT,           * sta_l = WT + 131072;
    unsigned short* cv1_h = WT + 262144,  * cv1_l = WT + 786432;
    unsigned short* cv2_h = WT + 1310720, * cv2_l = WT + 1835008;
    unsigned short* c1_h  = WT + 2359296, * c1_l  = WT + 3407872;
    unsigned short* cve_h = WT + 4456448, * cve_l = WT + 4980736;

    dim3 blk(256);

    // 0) conversions
    f2bf_vec<<<8192, blk, 0, stream>>>(x, xb);
    wsplit<<<512,  blk, 0, stream>>>(w_sta,   sta_h, sta_l);
    wsplit<<<2048, blk, 0, stream>>>(w_cv1,   cv1_h, cv1_l);
    wsplit<<<2048, blk, 0, stream>>>(w_cv2,   cv2_h, cv2_l);
    wsplit<<<4096, blk, 0, stream>>>(w_c1,    c1_h,  c1_l);
    wsplit<<<2048, blk, 0, stream>>>(w_cvend, cve_h, cve_l);

    // 1) x_aux = SiLU(sta(x)) -> bf16 [8,256,4096]
    {
        BSlots s; s.p[0] = xb; s.p[1] = xb + 1048576; s.p[2] = xb; s.p[3] = xb;
        gemm_mfma<0><<<dim3(16, 2, 8), blk, 0, stream>>>(
            sta_h, sta_l, nullptr, nullptr, 512, s, s, 2097152L,
            b_sta, nullptr, xaux, 256, nullptr, 0, 512);
    }

    // 2) RW pool cascade -> r1,r2,r3
    pool_rw_b<<<2048, blk, 0, stream>>>(xaux, r1);
    pool_rw_b<<<2048, blk, 0, stream>>>(r1, r2);
    pool_rw_b<<<2048, blk, 0, stream>>>(r2, r3);

    // 3) TMaxAvg cascade -> t1,t2,t3 (t1 overwrites xb, which is dead)
    pool_tma_b<<<2048, blk, 0, stream>>>(xaux, t1);
    pool_tma_b<<<2048, blk, 0, stream>>>(t1, t2);
    pool_tma_b<<<2048, blk, 0, stream>>>(t2, t3);

    // 4) merged cv1+cv2 -> Y2b channels [0,512)=cv1, [512,1024)=cv2
    {
        BSlots s1; s1.p[0] = xaux; s1.p[1] = t1; s1.p[2] = t2; s1.p[3] = t3;
        BSlots s2; s2.p[0] = xaux; s2.p[1] = r1; s2.p[2] = r2; s2.p[3] = r3;
        gemm_mfma<0><<<dim3(16, 8, 8), blk, 0, stream>>>(
            cv1_h, cv1_l, cv2_h, cv2_l, 1024, s1, s2, 1048576L,
            b_cv1, b_cv2, Y2b, 1024, nullptr, 0, 1024);
    }

    // 5) per batch-quad: dw chain -> a4q ; gated c1 -> gq ; cvend -> d_out
    for (int qd = 0; qd < 2; ++qd) {
        const int b0 = 4 * qd;
        lska_dw_quad<<<4096, blk, 0, stream>>>(Y2b, b0,
                                               w_dwh, b_dwh, w_dwv, b_dwv,
                                               w_ddwh, b_ddwh, w_ddwv, b_ddwv, a4q);
        {
            BSlots s; s.p[0] = a4q; s.p[1] = a4q + 1048576;
            s.p[2] = a4q + 2097152; s.p[3] = a4q + 3145728;
            gemm_mfma<1><<<dim3(16, 8, 4), blk, 0, stream>>>(
                c1_h, c1_l, nullptr, nullptr, 1024, s, s, 4194304L,
                b_c1, nullptr, gq, 1024, Y2b, b0, 1024);
        }
        {
            BSlots s; s.p[0] = gq; s.p[1] = gq + 1048576;
            s.p[2] = gq + 2097152; s.p[3] = gq + 3145728;
            gemm_mfma<2><<<dim3(16, 4, 4), blk, 0, stream>>>(
                cve_h, cve_l, nullptr, nullptr, 1024, s, s, 4194304L,
                b_cvend, nullptr, outf + (size_t)b0 * 2097152, 512,
                nullptr, 0, 1024);
        }
    }
}